// Round 10
// baseline (8292.326 us; speedup 1.0000x reference)
//
#include <hip/hip_runtime.h>

#define TT 1024
#define BB 256
#define CC 41

__device__ __forceinline__ float sigf(float x) {
    float t = __builtin_amdgcn_exp2f(-1.4426950408889634f * x);
    return __builtin_amdgcn_rcpf(1.0f + t);
}
__device__ __forceinline__ float tanhf_fast(float x) {
    float t = __builtin_amdgcn_exp2f(2.8853900817779268f * x);
    return fmaf(-2.0f, __builtin_amdgcn_rcpf(t + 1.0f), 1.0f);
}
__device__ __forceinline__ float lane_bcast(float v, int k) {
    return __uint_as_float(__builtin_amdgcn_readlane(__float_as_uint(v), k));
}

// ---------------------------------------------------------------------------
// Split-K fused LSTM, TWO batch rows per block. 512 threads, 8 waves.
// Wave w: gate block gsel=w>>1 (64 gates), K-half = w&1. Both rows share the
// same per-thread weights (wx[KH]+wh[32]) -> weight-fetch/AGPR cost amortized.
//
// WHY (rounds 0/5/7/8/9): every register/LDS restructure left the K=128
// layer at 1980-2220us. The invariant was the SCHEDULE: 512 blocks on 256
// CUs, ~8 resident waves/CU, 1 barrier/step -> a ~2600cyc/step latency chain
// (barrier + 120cyc ds_read + serial act chain) that 8 lockstep waves can't
// hide, times TWO sequential block passes. Pairing rows: 256 blocks = 1
// block/CU, ONE pass, 2x work per barrier fills the measured ~26% idle.
//
// Per step (ONE barrier):
//  - pipelined read of next step's x for both rows (2 ds_read_b32)
//  - global prefetch of x_{s+2} for both rows (issue early, land late)
//  - 16 ds_read partials (both rows, both halves); latency hidden by x-FMAs
//  - x-part row0/row1: KH x { readlane ; fma } each
//  - acts + c/h updates (replicated per-lane; lane u = unit u)
//  - h-part row0/row1: 32 x { readlane(hv_r, halfu*32+j) ; fma } each
//  - write partial[s&1][row][half][gate]; land prefetch; barrier
// ---------------------------------------------------------------------------
template <int K>
__global__ __launch_bounds__(512)
__attribute__((amdgpu_waves_per_eu(2, 2)))
void lstm_pair(
    const float* __restrict__ xin,   // [B,T,K]
    const float* __restrict__ w_ih,  // [2,256,K]
    const float* __restrict__ w_hh,  // [2,256,64]
    const float* __restrict__ bias,  // [2,256]
    float* __restrict__ hout)        // [B,T,128], dir writes its 64-half
{
    constexpr int KH = ((K + 7) / 8) * 4;   // per-half K length (mult of 4)
    constexpr int KP = 2 * KH;              // padded x row length
    const int bp = blockIdx.x;              // row pair: rows 2bp, 2bp+1
    const int dir = blockIdx.y;
    const int tid = threadIdx.x;
    const int lane = tid & 63;
    const int w = tid >> 6;                        // 0..7 (wave-uniform)
    const int halfu = __builtin_amdgcn_readfirstlane(w & 1);   // uniform!
    const int gsel = w >> 1;                       // 0..3 = act block (i,f,g,o)
    const int G = gsel * 64 + lane;                // gate 0..255

    // ---- per-thread half-weights (shared by both rows) ----
    float wx[KH];
    {
        const volatile float* wr =
            w_ih + ((size_t)dir * 256 + G) * K + halfu * KH;
#pragma unroll
        for (int j = 0; j < KH; ++j)
            wx[j] = (halfu * KH + j < K) ? wr[j] : 0.f;   // pad tail (K=39)
    }
    float wh[32];
    {
        const volatile float* hr =
            w_hh + ((size_t)dir * 256 + G) * 64 + halfu * 32;
#pragma unroll
        for (int j = 0; j < 32; ++j) wh[j] = hr[j];
    }
    const float bg = halfu ? 0.f : bias[dir * 256 + G];

    __shared__ __align__(16) float xs[3][2][KP];    // rotating x staging, 2 rows
    __shared__ float part[2][2][2][256];            // [parity][row][half][gate]

    const float* xb0 = xin + (size_t)(2 * bp) * TT * K;
    const float* xb1 = xin + (size_t)(2 * bp + 1) * TT * K;
    float* hob0 = hout + (size_t)(2 * bp) * TT * 128 + dir * 64;
    float* hob1 = hout + (size_t)(2 * bp + 1) * TT * 128 + dir * 64;

    // per-lane x read offset (lane j -> element j of this wave's K-half;
    // clamp keeps addresses in-bounds when KH<64 -- readlane only uses j<KH)
    const int cl = (KH < 64) ? ((lane < KH) ? lane : (KH - 1)) : lane;
    const int xoff = halfu * KH + cl;

    // prologue: stage x(s=0,1) for both rows; zero pads; zero part[1] so the
    // unconditional step-0 "previous update" keeps c=h=0.
    {
        const int t0 = dir ? (TT - 1) : 0;
        const int t1 = dir ? (TT - 2) : 1;
        if (tid < K) {
            xs[0][0][tid] = xb0[(size_t)t0 * K + tid];
            xs[1][0][tid] = xb0[(size_t)t1 * K + tid];
        } else if (tid >= 256 && tid < 256 + K) {
            const int k2 = tid - 256;
            xs[0][1][k2] = xb1[(size_t)t0 * K + k2];
            xs[1][1][k2] = xb1[(size_t)t1 * K + k2];
        }
        if (KP > K) {
            if (tid >= K && tid < KP) {
                xs[0][0][tid] = 0.f; xs[1][0][tid] = 0.f; xs[2][0][tid] = 0.f;
            }
            if (tid >= 256 + K && tid < 256 + KP) {
                const int k2 = tid - 256;
                xs[0][1][k2] = 0.f; xs[1][1][k2] = 0.f; xs[2][1][k2] = 0.f;
            }
        }
        float* pz = &part[1][0][0][0];   // 1024 floats
        pz[tid] = 0.f; pz[tid + 512] = 0.f;
    }

    float c0 = 0.f, c1 = 0.f, hv0 = 0.f, hv1 = 0.f;
    int rcn = 1, rw = 2;   // next-x slot ((s+1)%3), staging slot ((s+2)%3)
    __syncthreads();

    float xc0 = xs[0][0][xoff];   // x for step 0 (lane-distinct)
    float xc1 = xs[0][1][xoff];

    for (int s = 0; s < TT; ++s) {
        // ---- pipelined read of next step's x (staged two steps ago) ----
        float xn0 = 0.f, xn1 = 0.f;
        if (s + 1 < TT) { xn0 = xs[rcn][0][xoff]; xn1 = xs[rcn][1][xoff]; }

        // ---- issue global prefetch of x_{s+2} ----
        const bool pf = (s + 2 < TT);
        float xf = 0.f;
        if (pf) {
            const int tp = dir ? (TT - 3 - s) : (s + 2);
            if (tid < K)                            xf = xb0[(size_t)tp * K + tid];
            else if (tid >= 256 && tid < 256 + K)   xf = xb1[(size_t)tp * K + (tid - 256)];
        }

        // ---- previous step's partials, both rows (16 ds_read) ----
        const float* p00 = part[(s + 1) & 1][0][0];
        const float* p01 = part[(s + 1) & 1][0][1];
        const float* p10 = part[(s + 1) & 1][1][0];
        const float* p11 = part[(s + 1) & 1][1][1];
        const float ai0 = p00[lane]       + p01[lane];
        const float af0 = p00[64 + lane]  + p01[64 + lane];
        const float ag0 = p00[128 + lane] + p01[128 + lane];
        const float ao0 = p00[192 + lane] + p01[192 + lane];
        const float ai1 = p10[lane]       + p11[lane];
        const float af1 = p10[64 + lane]  + p11[64 + lane];
        const float ag1 = p10[128 + lane] + p11[128 + lane];
        const float ao1 = p10[192 + lane] + p11[192 + lane];

        // ---- x-part both rows: readlane broadcast (values ready) ----
        float a0p0 = bg, a0p1 = 0.f, a0p2 = 0.f, a0p3 = 0.f;
        float a1p0 = bg, a1p1 = 0.f, a1p2 = 0.f, a1p3 = 0.f;
#pragma unroll
        for (int j = 0; j < KH; ++j) {
            const float xk0 = lane_bcast(xc0, j);
            const float xk1 = lane_bcast(xc1, j);
            if ((j & 3) == 0)      { a0p0 = fmaf(xk0, wx[j], a0p0); a1p0 = fmaf(xk1, wx[j], a1p0); }
            else if ((j & 3) == 1) { a0p1 = fmaf(xk0, wx[j], a0p1); a1p1 = fmaf(xk1, wx[j], a1p1); }
            else if ((j & 3) == 2) { a0p2 = fmaf(xk0, wx[j], a0p2); a1p2 = fmaf(xk1, wx[j], a1p2); }
            else                   { a0p3 = fmaf(xk0, wx[j], a0p3); a1p3 = fmaf(xk1, wx[j], a1p3); }
        }

        // ---- acts + c/h updates (replicated; lane u holds unit u) ----
        c0 = fmaf(sigf(af0), c0, sigf(ai0) * tanhf_fast(ag0));
        hv0 = sigf(ao0) * tanhf_fast(c0);
        c1 = fmaf(sigf(af1), c1, sigf(ai1) * tanhf_fast(ag1));
        hv1 = sigf(ao1) * tanhf_fast(c1);
        if (s) {
            const int tprev = dir ? (TT - s) : (s - 1);
            if (w == 0) hob0[(size_t)tprev * 128 + lane] = hv0;   // fire-and-forget
            if (w == 2) hob1[(size_t)tprev * 128 + lane] = hv1;
        }

        // ---- h-part both rows: readlane(hv_r, halfu*32+j) ----
#pragma unroll
        for (int j = 0; j < 32; ++j) {
            const float hk0 = lane_bcast(hv0, halfu * 32 + j);
            const float hk1 = lane_bcast(hv1, halfu * 32 + j);
            if ((j & 3) == 0)      { a0p0 = fmaf(hk0, wh[j], a0p0); a1p0 = fmaf(hk1, wh[j], a1p0); }
            else if ((j & 3) == 1) { a0p1 = fmaf(hk0, wh[j], a0p1); a1p1 = fmaf(hk1, wh[j], a1p1); }
            else if ((j & 3) == 2) { a0p2 = fmaf(hk0, wh[j], a0p2); a1p2 = fmaf(hk1, wh[j], a1p2); }
            else                   { a0p3 = fmaf(hk0, wh[j], a0p3); a1p3 = fmaf(hk1, wh[j], a1p3); }
        }

        // ---- this step's partials ----
        part[s & 1][0][halfu][G] = (a0p0 + a0p1) + (a0p2 + a0p3);
        part[s & 1][1][halfu][G] = (a1p0 + a1p1) + (a1p2 + a1p3);

        // ---- land prefetched x ----
        if (pf) {
            if (tid < K)                          xs[rw][0][tid] = xf;
            else if (tid >= 256 && tid < 256 + K) xs[rw][1][tid - 256] = xf;
        }
        __syncthreads();

        xc0 = xn0; xc1 = xn1;
        rcn = (rcn == 2) ? 0 : rcn + 1;
        rw = (rw == 2) ? 0 : rw + 1;
    }

    // epilogue: h[TT-1] for both rows from the last partials
    {
        const float* p00 = part[(TT - 1) & 1][0][0];
        const float* p01 = part[(TT - 1) & 1][0][1];
        const float* p10 = part[(TT - 1) & 1][1][0];
        const float* p11 = part[(TT - 1) & 1][1][1];
        const int tlast = dir ? 0 : (TT - 1);
        {
            const float ai = p00[lane] + p01[lane];
            const float af = p00[64 + lane] + p01[64 + lane];
            const float ag = p00[128 + lane] + p01[128 + lane];
            const float ao = p00[192 + lane] + p01[192 + lane];
            const float cf = fmaf(sigf(af), c0, sigf(ai) * tanhf_fast(ag));
            if (w == 0) hob0[(size_t)tlast * 128 + lane] = sigf(ao) * tanhf_fast(cf);
        }
        {
            const float ai = p10[lane] + p11[lane];
            const float af = p10[64 + lane] + p11[64 + lane];
            const float ag = p10[128 + lane] + p11[128 + lane];
            const float ao = p10[192 + lane] + p11[192 + lane];
            const float cf = fmaf(sigf(af), c1, sigf(ai) * tanhf_fast(ag));
            if (w == 2) hob1[(size_t)tlast * 128 + lane] = sigf(ao) * tanhf_fast(cf);
        }
    }
}

// emissions = feats @ lin_w^T + lin_b ; block tile = 64 (b,t) rows x 41 classes
__global__ __launch_bounds__(256, 2) void emis_kernel(
    const float* __restrict__ feats,  // [B*T,128]
    const float* __restrict__ lw,     // [41,128]
    const float* __restrict__ lb,     // [41]
    float* __restrict__ e)            // [B*T,41]
{
    __shared__ float sf[64 * 132];
    __shared__ float swt[41 * 132];
    const int tid = threadIdx.x;
    const size_t bt0 = (size_t)blockIdx.x * 64;

    const float4* fs = (const float4*)(feats + bt0 * 128);
#pragma unroll
    for (int q = 0; q < 8; ++q) {
        const int idx = tid + q * 256;
        const int row = idx >> 5, col = idx & 31;
        *(float4*)&sf[row * 132 + col * 4] = fs[idx];
    }
    for (int idx = tid; idx < 41 * 32; idx += 256) {
        const int row = idx >> 5, col = idx & 31;
        *(float4*)&swt[row * 132 + col * 4] = ((const float4*)lw)[idx];
    }
    __syncthreads();

    const int btg = tid >> 4;
    const int cg = tid & 15;
    const int c0 = cg * 3;
    float acc[4][3];
#pragma unroll
    for (int i = 0; i < 4; ++i)
#pragma unroll
        for (int j = 0; j < 3; ++j) acc[i][j] = 0.f;

    for (int k = 0; k < 128; k += 4) {
        float4 fv[4], wv[3];
#pragma unroll
        for (int i = 0; i < 4; ++i) fv[i] = *(const float4*)&sf[(btg * 4 + i) * 132 + k];
#pragma unroll
        for (int j = 0; j < 3; ++j) {
            const int c = (c0 + j < CC) ? (c0 + j) : (CC - 1);
            wv[j] = *(const float4*)&swt[c * 132 + k];
        }
#pragma unroll
        for (int i = 0; i < 4; ++i)
#pragma unroll
            for (int j = 0; j < 3; ++j) {
                acc[i][j] = fmaf(fv[i].x, wv[j].x, acc[i][j]);
                acc[i][j] = fmaf(fv[i].y, wv[j].y, acc[i][j]);
                acc[i][j] = fmaf(fv[i].z, wv[j].z, acc[i][j]);
                acc[i][j] = fmaf(fv[i].w, wv[j].w, acc[i][j]);
            }
    }
    __syncthreads();
    float* so = sf;
#pragma unroll
    for (int i = 0; i < 4; ++i)
#pragma unroll
        for (int j = 0; j < 3; ++j) {
            const int c = c0 + j;
            if (c < CC) so[(btg * 4 + i) * CC + c] = acc[i][j] + lb[c];
        }
    __syncthreads();
    float* eo = e + bt0 * CC;
    for (int q = tid; q < 64 * CC; q += 256) eo[q] = so[q];
}

// One wave per batch row; backpointers in LDS; in-kernel backtrace.
__global__ __launch_bounds__(64, 1) void viterbi_kernel(
    const float* __restrict__ e, const float* __restrict__ st,
    const float* __restrict__ en, const float* __restrict__ tr,
    int* __restrict__ out)
{
    const int b = blockIdx.x;
    const int lane = threadIdx.x;
    __shared__ unsigned char bp[TT][CC];
    __shared__ float sc[2][CC];
    const int c = (lane < CC) ? lane : (CC - 1);
    float trc[CC];
#pragma unroll
    for (int p = 0; p < CC; ++p) trc[p] = tr[p * CC + c];

    const float* eb = e + (size_t)b * TT * CC;
    const float NEG = -3.0e38f;
    if (lane < CC) sc[0][lane] = st[lane] + eb[lane];
    __syncthreads();

    for (int t = 1; t < TT; ++t) {
        const float* scp = sc[(t - 1) & 1];
        float best = NEG;
        int bi = 0;
#pragma unroll
        for (int p = 0; p < CC; ++p) {
            const float v = scp[p] + trc[p];
            if (v > best) { best = v; bi = p; }   // strict > : first-index ties
        }
        if (lane < CC) {
            sc[t & 1][lane] = best + eb[(size_t)t * CC + lane];
            bp[t][lane] = (unsigned char)bi;
        }
        __syncthreads();
    }

    float fin = (lane < CC) ? sc[(TT - 1) & 1][lane] + en[lane] : NEG;
    int idx = lane;
#pragma unroll
    for (int off = 32; off; off >>= 1) {
        const float v2 = __shfl_down(fin, off, 64);
        const int i2 = __shfl_down(idx, off, 64);
        if (v2 > fin || (v2 == fin && i2 < idx)) { fin = v2; idx = i2; }
    }
    int tag = __shfl(idx, 0, 64);
    if (lane == 0) {
        int* ob = out + (size_t)b * TT;
        ob[TT - 1] = tag;
        for (int t = TT - 1; t >= 1; --t) {
            tag = bp[t][tag];
            ob[t - 1] = tag;
        }
    }
}

extern "C" void kernel_launch(void* const* d_in, const int* in_sizes, int n_in,
                              void* d_out, int out_size, void* d_ws, size_t ws_size,
                              hipStream_t stream) {
    const float* x       = (const float*)d_in[0];   // [B,T,39]
    const float* w_ih_l0 = (const float*)d_in[1];   // [2,256,39]
    const float* w_hh_l0 = (const float*)d_in[2];   // [2,256,64]
    const float* b_l0    = (const float*)d_in[3];   // [2,256]
    const float* w_ih_r  = (const float*)d_in[4];   // [2,2,256,128]
    const float* w_hh_r  = (const float*)d_in[5];   // [2,2,256,64]
    const float* b_r     = (const float*)d_in[6];   // [2,2,256]
    const float* lin_w   = (const float*)d_in[7];   // [41,128]
    const float* lin_b   = (const float*)d_in[8];   // [41]
    const float* crf_s   = (const float*)d_in[9];   // [41]
    const float* crf_e   = (const float*)d_in[10];  // [41]
    const float* crf_t   = (const float*)d_in[11];  // [41,41]
    int* out = (int*)d_out;

    float* buf0 = (float*)d_ws;                         // [B,T,128] = 128 MiB
    float* buf1 = buf0 + (size_t)BB * TT * 128;         // [B,T,128] = 128 MiB

    dim3 grid(BB / 2, 2);   // 128 row-pairs x 2 dirs = 256 blocks = 1/CU
    // layer 0 (input dim 39): buf0 <- x
    lstm_pair<39><<<grid, 512, 0, stream>>>(x, w_ih_l0, w_hh_l0, b_l0, buf0);
    // layer 1: buf1 <- buf0
    lstm_pair<128><<<grid, 512, 0, stream>>>(buf0, w_ih_r, w_hh_r, b_r, buf1);
    // layer 2: buf0 <- buf1
    lstm_pair<128><<<grid, 512, 0, stream>>>(
        buf1, w_ih_r + 2 * 256 * 128, w_hh_r + 2 * 256 * 64, b_r + 2 * 256, buf0);
    // emissions: buf1 <- buf0, [B*T,41]
    emis_kernel<<<BB * TT / 64, 256, 0, stream>>>(buf0, lin_w, lin_b, buf1);
    // viterbi + backtrace
    viterbi_kernel<<<BB, 64, 0, stream>>>(buf1, crf_s, crf_e, crf_t, out);
}

// Round 11
// 5738.200 us; speedup vs baseline: 1.4451x; 1.4451x over previous
//
#include <hip/hip_runtime.h>

#define TT 1024
#define BB 256
#define CC 41

__device__ __forceinline__ float sigf(float x) {
    float t = __builtin_amdgcn_exp2f(-1.4426950408889634f * x);
    return __builtin_amdgcn_rcpf(1.0f + t);
}
__device__ __forceinline__ float tanhf_fast(float x) {
    float t = __builtin_amdgcn_exp2f(2.8853900817779268f * x);
    return fmaf(-2.0f, __builtin_amdgcn_rcpf(t + 1.0f), 1.0f);
}
__device__ __forceinline__ float lane_bcast(float v, int k) {
    return __uint_as_float(__builtin_amdgcn_readlane(__float_as_uint(v), k));
}

// ---------------------------------------------------------------------------
// Split-K fused LSTM (round-5 structure, the measured optimum of this design
// family) + step-loop unroll x4 with a 4-slot x rotation so ALL per-step LDS
// indices (part parity, xs slots) are compile-time constants.
//
// One (batch row, direction) per block, 512 threads. Wave w (of 8): gate
// block gsel=w>>1 (64 gates = one activation type), K-half = w&1. Per-thread
// weights wx[KH]+wh[32] (96 floats at K=128).
//
// Per step (ONE barrier):
//  - issue global prefetch of x_{s+2} (lands in slot (s+2)&3 pre-barrier)
//  - read both halves' partials for unit u=lane (8 ds_read, static offsets)
//  - x-part: KH/4 broadcast float4 LDS reads from slot s&3 + KH FMAs
//  - acts + c/h update replicated per-lane (lane u of every wave = unit u)
//  - h-part: 32x { readlane(hv, halfu*32+j) ; fma }  (uniform lane index)
//  - write partial[s&1][half][gate]; land prefetch; barrier
// ---------------------------------------------------------------------------
template <int K>
__global__ __launch_bounds__(512, 2) void lstm_half(
    const float* __restrict__ xin,   // [B,T,K]
    const float* __restrict__ w_ih,  // [2,256,K]
    const float* __restrict__ w_hh,  // [2,256,64]
    const float* __restrict__ bias,  // [2,256]
    float* __restrict__ hout)        // [B,T,128], dir writes its 64-half
{
    constexpr int KH = ((K + 7) / 8) * 4;   // per-half K length (mult of 4)
    constexpr int KP = 2 * KH;              // padded x row length
    const int b = blockIdx.x;
    const int dir = blockIdx.y;
    const int tid = threadIdx.x;
    const int lane = tid & 63;
    const int w = tid >> 6;                        // 0..7 (wave-uniform)
    const int halfu = __builtin_amdgcn_readfirstlane(w & 1);   // uniform!
    const int gsel = w >> 1;                       // 0..3 = act block (i,f,g,o)
    const int G = gsel * 64 + lane;                // gate 0..255

    // ---- per-thread half-weights ----
    float wx[KH];
    {
        const float* wr = w_ih + ((size_t)dir * 256 + G) * K + halfu * KH;
#pragma unroll
        for (int j = 0; j < KH; ++j)
            wx[j] = (halfu * KH + j < K) ? wr[j] : 0.f;   // pad tail (K=39)
    }
    float wh[32];
    {
        const float* hr = w_hh + ((size_t)dir * 256 + G) * 64 + halfu * 32;
#pragma unroll
        for (int j = 0; j < 32; ++j) wh[j] = hr[j];
    }
    const float bg = halfu ? 0.f : bias[dir * 256 + G];

    __shared__ __align__(16) float xs[4][KP];     // 4-slot rotating x staging
    __shared__ float part[2][2][256];             // [parity][half][gate]

    const float* xb = xin + (size_t)b * TT * K;
    float* hob = hout + (size_t)b * TT * 128 + dir * 64;

    // prologue: stage x for s=0,1; zero all slots' pad lanes; zero part[1]
    // so step-0's "previous update" is a no-op (keeps c=h=0).
    if (tid < K) {
        const int t0 = dir ? (TT - 1) : 0;
        const int t1 = dir ? (TT - 2) : 1;
        xs[0][tid] = xb[(size_t)t0 * K + tid];
        xs[1][tid] = xb[(size_t)t1 * K + tid];
    }
    if (KP > K && tid >= K && tid < KP) {
        xs[0][tid] = 0.f; xs[1][tid] = 0.f; xs[2][tid] = 0.f; xs[3][tid] = 0.f;
    }
    (&part[1][0][0])[tid] = 0.f;   // 512 floats = part[1] entirely

    float c = 0.f, hv = 0.f;
    __syncthreads();

    for (int sb = 0; sb < TT; sb += 4) {
#pragma unroll
        for (int U = 0; U < 4; ++U) {
            const int s = sb + U;   // sb % 4 == 0 -> s&3==U, s&1==U&1 (static)

            // ---- issue prefetch of x_{s+2} (lands before the barrier) ----
            const bool pf = (s + 2 < TT) && (tid < K);
            float xf = 0.f;
            if (pf) {
                const int tp = dir ? (TT - 3 - s) : (s + 2);
                xf = xb[(size_t)tp * K + tid];
            }

            // ---- previous step's partials -> acts for unit u=lane ----
            const float* pp0 = part[(s + 1) & 1][0];
            const float* pp1 = part[(s + 1) & 1][1];
            const float ai = pp0[lane]       + pp1[lane];
            const float af = pp0[64 + lane]  + pp1[64 + lane];
            const float ag = pp0[128 + lane] + pp1[128 + lane];
            const float ao = pp0[192 + lane] + pp1[192 + lane];
            const float iv = sigf(ai), fv = sigf(af);
            const float gv = tanhf_fast(ag), ov = sigf(ao);
            c = fmaf(fv, c, iv * gv);
            hv = ov * tanhf_fast(c);
            if (s && w == 0) {
                const int tprev = dir ? (TT - s) : (s - 1);
                hob[(size_t)tprev * 128 + lane] = hv;   // fire-and-forget
            }

            // ---- x-part: broadcast float4 reads of this wave's K-half ----
            float ap0 = bg, ap1 = 0.f, ap2 = 0.f, ap3 = 0.f;
            const float4* xv4 = (const float4*)(xs[s & 3] + halfu * KH);
#pragma unroll
            for (int q = 0; q < KH / 4; ++q) {
                const float4 xv = xv4[q];
                ap0 = fmaf(xv.x, wx[4 * q + 0], ap0);
                ap1 = fmaf(xv.y, wx[4 * q + 1], ap1);
                ap2 = fmaf(xv.z, wx[4 * q + 2], ap2);
                ap3 = fmaf(xv.w, wx[4 * q + 3], ap3);
            }

            // ---- h-part: readlane broadcast, k = halfu*32 + j (uniform) ----
#pragma unroll
            for (int j = 0; j < 32; ++j) {
                const float hk = lane_bcast(hv, halfu * 32 + j);
                if ((j & 3) == 0)      ap0 = fmaf(hk, wh[j], ap0);
                else if ((j & 3) == 1) ap1 = fmaf(hk, wh[j], ap1);
                else if ((j & 3) == 2) ap2 = fmaf(hk, wh[j], ap2);
                else                   ap3 = fmaf(hk, wh[j], ap3);
            }

            // ---- this step's partial ----
            part[s & 1][halfu][G] = (ap0 + ap1) + (ap2 + ap3);

            // ---- land prefetched x in slot (s+2)&3 (static) ----
            if (pf) xs[(s + 2) & 3][tid] = xf;
            __syncthreads();
        }
    }

    // epilogue: h[TT-1] from the last partials
    {
        const float* pp0 = part[(TT - 1) & 1][0];
        const float* pp1 = part[(TT - 1) & 1][1];
        const float ai = pp0[lane]       + pp1[lane];
        const float af = pp0[64 + lane]  + pp1[64 + lane];
        const float ag = pp0[128 + lane] + pp1[128 + lane];
        const float ao = pp0[192 + lane] + pp1[192 + lane];
        const float cf = fmaf(sigf(af), c, sigf(ai) * tanhf_fast(ag));
        const float hf = sigf(ao) * tanhf_fast(cf);
        if (w == 0) {
            const int tlast = dir ? 0 : (TT - 1);
            hob[(size_t)tlast * 128 + lane] = hf;
        }
    }
}

// emissions = feats @ lin_w^T + lin_b ; block tile = 64 (b,t) rows x 41 classes
__global__ __launch_bounds__(256, 2) void emis_kernel(
    const float* __restrict__ feats,  // [B*T,128]
    const float* __restrict__ lw,     // [41,128]
    const float* __restrict__ lb,     // [41]
    float* __restrict__ e)            // [B*T,41]
{
    __shared__ float sf[64 * 132];
    __shared__ float swt[41 * 132];
    const int tid = threadIdx.x;
    const size_t bt0 = (size_t)blockIdx.x * 64;

    const float4* fs = (const float4*)(feats + bt0 * 128);
#pragma unroll
    for (int q = 0; q < 8; ++q) {
        const int idx = tid + q * 256;
        const int row = idx >> 5, col = idx & 31;
        *(float4*)&sf[row * 132 + col * 4] = fs[idx];
    }
    for (int idx = tid; idx < 41 * 32; idx += 256) {
        const int row = idx >> 5, col = idx & 31;
        *(float4*)&swt[row * 132 + col * 4] = ((const float4*)lw)[idx];
    }
    __syncthreads();

    const int btg = tid >> 4;
    const int cg = tid & 15;
    const int c0 = cg * 3;
    float acc[4][3];
#pragma unroll
    for (int i = 0; i < 4; ++i)
#pragma unroll
        for (int j = 0; j < 3; ++j) acc[i][j] = 0.f;

    for (int k = 0; k < 128; k += 4) {
        float4 fv[4], wv[3];
#pragma unroll
        for (int i = 0; i < 4; ++i) fv[i] = *(const float4*)&sf[(btg * 4 + i) * 132 + k];
#pragma unroll
        for (int j = 0; j < 3; ++j) {
            const int c = (c0 + j < CC) ? (c0 + j) : (CC - 1);
            wv[j] = *(const float4*)&swt[c * 132 + k];
        }
#pragma unroll
        for (int i = 0; i < 4; ++i)
#pragma unroll
            for (int j = 0; j < 3; ++j) {
                acc[i][j] = fmaf(fv[i].x, wv[j].x, acc[i][j]);
                acc[i][j] = fmaf(fv[i].y, wv[j].y, acc[i][j]);
                acc[i][j] = fmaf(fv[i].z, wv[j].z, acc[i][j]);
                acc[i][j] = fmaf(fv[i].w, wv[j].w, acc[i][j]);
            }
    }
    __syncthreads();
    float* so = sf;
#pragma unroll
    for (int i = 0; i < 4; ++i)
#pragma unroll
        for (int j = 0; j < 3; ++j) {
            const int c = c0 + j;
            if (c < CC) so[(btg * 4 + i) * CC + c] = acc[i][j] + lb[c];
        }
    __syncthreads();
    float* eo = e + bt0 * CC;
    for (int q = tid; q < 64 * CC; q += 256) eo[q] = so[q];
}

// One wave per batch row; backpointers in LDS; in-kernel backtrace.
__global__ __launch_bounds__(64, 1) void viterbi_kernel(
    const float* __restrict__ e, const float* __restrict__ st,
    const float* __restrict__ en, const float* __restrict__ tr,
    int* __restrict__ out)
{
    const int b = blockIdx.x;
    const int lane = threadIdx.x;
    __shared__ unsigned char bp[TT][CC];
    __shared__ float sc[2][CC];
    const int c = (lane < CC) ? lane : (CC - 1);
    float trc[CC];
#pragma unroll
    for (int p = 0; p < CC; ++p) trc[p] = tr[p * CC + c];

    const float* eb = e + (size_t)b * TT * CC;
    const float NEG = -3.0e38f;
    if (lane < CC) sc[0][lane] = st[lane] + eb[lane];
    __syncthreads();

    for (int t = 1; t < TT; ++t) {
        const float* scp = sc[(t - 1) & 1];
        float best = NEG;
        int bi = 0;
#pragma unroll
        for (int p = 0; p < CC; ++p) {
            const float v = scp[p] + trc[p];
            if (v > best) { best = v; bi = p; }   // strict > : first-index ties
        }
        if (lane < CC) {
            sc[t & 1][lane] = best + eb[(size_t)t * CC + lane];
            bp[t][lane] = (unsigned char)bi;
        }
        __syncthreads();
    }

    float fin = (lane < CC) ? sc[(TT - 1) & 1][lane] + en[lane] : NEG;
    int idx = lane;
#pragma unroll
    for (int off = 32; off; off >>= 1) {
        const float v2 = __shfl_down(fin, off, 64);
        const int i2 = __shfl_down(idx, off, 64);
        if (v2 > fin || (v2 == fin && i2 < idx)) { fin = v2; idx = i2; }
    }
    int tag = __shfl(idx, 0, 64);
    if (lane == 0) {
        int* ob = out + (size_t)b * TT;
        ob[TT - 1] = tag;
        for (int t = TT - 1; t >= 1; --t) {
            tag = bp[t][tag];
            ob[t - 1] = tag;
        }
    }
}

extern "C" void kernel_launch(void* const* d_in, const int* in_sizes, int n_in,
                              void* d_out, int out_size, void* d_ws, size_t ws_size,
                              hipStream_t stream) {
    const float* x       = (const float*)d_in[0];   // [B,T,39]
    const float* w_ih_l0 = (const float*)d_in[1];   // [2,256,39]
    const float* w_hh_l0 = (const float*)d_in[2];   // [2,256,64]
    const float* b_l0    = (const float*)d_in[3];   // [2,256]
    const float* w_ih_r  = (const float*)d_in[4];   // [2,2,256,128]
    const float* w_hh_r  = (const float*)d_in[5];   // [2,2,256,64]
    const float* b_r     = (const float*)d_in[6];   // [2,2,256]
    const float* lin_w   = (const float*)d_in[7];   // [41,128]
    const float* lin_b   = (const float*)d_in[8];   // [41]
    const float* crf_s   = (const float*)d_in[9];   // [41]
    const float* crf_e   = (const float*)d_in[10];  // [41]
    const float* crf_t   = (const float*)d_in[11];  // [41,41]
    int* out = (int*)d_out;

    float* buf0 = (float*)d_ws;                         // [B,T,128] = 128 MiB
    float* buf1 = buf0 + (size_t)BB * TT * 128;         // [B,T,128] = 128 MiB

    dim3 grid(BB, 2);
    // layer 0 (input dim 39): buf0 <- x
    lstm_half<39><<<grid, 512, 0, stream>>>(x, w_ih_l0, w_hh_l0, b_l0, buf0);
    // layer 1: buf1 <- buf0
    lstm_half<128><<<grid, 512, 0, stream>>>(buf0, w_ih_r, w_hh_r, b_r, buf1);
    // layer 2: buf0 <- buf1
    lstm_half<128><<<grid, 512, 0, stream>>>(
        buf1, w_ih_r + 2 * 256 * 128, w_hh_r + 2 * 256 * 64, b_r + 2 * 256, buf0);
    // emissions: buf1 <- buf0, [B*T,41]
    emis_kernel<<<BB * TT / 64, 256, 0, stream>>>(buf0, lin_w, lin_b, buf1);
    // viterbi + backtrace
    viterbi_kernel<<<BB, 64, 0, stream>>>(buf1, crf_s, crf_e, crf_t, out);
}

// Round 12
// 5249.480 us; speedup vs baseline: 1.5796x; 1.0931x over previous
//
#include <hip/hip_runtime.h>

#define TT 1024
#define BB 256
#define CC 41

__device__ __forceinline__ float sigf(float x) {
    float t = __builtin_amdgcn_exp2f(-1.4426950408889634f * x);
    return __builtin_amdgcn_rcpf(1.0f + t);
}
__device__ __forceinline__ float tanhf_fast(float x) {
    float t = __builtin_amdgcn_exp2f(2.8853900817779268f * x);
    return fmaf(-2.0f, __builtin_amdgcn_rcpf(t + 1.0f), 1.0f);
}
__device__ __forceinline__ float lane_bcast(float v, int k) {
    return __uint_as_float(__builtin_amdgcn_readlane(__float_as_uint(v), k));
}

// ---------------------------------------------------------------------------
// Dual-direction split-K fused LSTM. ONE batch row per block, BOTH directions:
// 1024 threads = 16 waves; waves 0-7 run dir0, waves 8-15 run dir1, each wave
// executing the exact round-11 per-wave program (gate block gsel, K-half)
// against its direction's own xs/part arrays. The two streams are fully
// independent and only share the block barrier (identical lockstep work).
//
// WHY (round-11 counters): 512 blocks ran as TWO sequential 1-block/CU passes
// with only 8 resident waves (Occupancy 24%) -- per-step latency bubbles
// (barrier drain, ds_read latency, serial act chain) are the measured ~27%
// idle. Merging dirs: 256 blocks = 1 block/CU, ONE pass, 16 resident waves
// whose independent streams fill each other's bubbles. Per-thread work is
// UNCHANGED (round-10's failure was doubling per-thread work; this doesn't).
//
// Step-loop unroll x4 kept: all LDS indices compile-time static.
// ---------------------------------------------------------------------------
template <int K>
__global__ __launch_bounds__(1024, 4) void lstm_dual(
    const float* __restrict__ xin,   // [B,T,K]
    const float* __restrict__ w_ih,  // [2,256,K]
    const float* __restrict__ w_hh,  // [2,256,64]
    const float* __restrict__ bias,  // [2,256]
    float* __restrict__ hout)        // [B,T,128], dir writes its 64-half
{
    constexpr int KH = ((K + 7) / 8) * 4;   // per-half K length (mult of 4)
    constexpr int KP = 2 * KH;              // padded x row length
    const int b = blockIdx.x;
    const int tid = threadIdx.x;
    const int t512 = tid & 511;                    // index within dir-half
    const int lane = tid & 63;
    const int w8 = t512 >> 6;                      // 0..7 (wave-uniform)
    const int diru = __builtin_amdgcn_readfirstlane(tid >> 9);   // 0/1 uniform
    const int halfu = __builtin_amdgcn_readfirstlane(w8 & 1);    // uniform
    const int gsel = w8 >> 1;                      // 0..3 = act block (i,f,g,o)
    const int G = gsel * 64 + lane;                // gate 0..255

    // ---- per-thread half-weights ----
    float wx[KH];
    {
        const float* wr = w_ih + ((size_t)diru * 256 + G) * K + halfu * KH;
#pragma unroll
        for (int j = 0; j < KH; ++j)
            wx[j] = (halfu * KH + j < K) ? wr[j] : 0.f;   // pad tail (K=39)
    }
    float wh[32];
    {
        const float* hr = w_hh + ((size_t)diru * 256 + G) * 64 + halfu * 32;
#pragma unroll
        for (int j = 0; j < 32; ++j) wh[j] = hr[j];
    }
    const float bg = halfu ? 0.f : bias[diru * 256 + G];

    __shared__ __align__(16) float xs[2][4][KP];   // per-dir 4-slot x staging
    __shared__ float part[2][2][2][256];           // [dir][parity][half][gate]

    const float* xb = xin + (size_t)b * TT * K;
    float* hob = hout + (size_t)b * TT * 128 + diru * 64;

    // prologue: each dir stages its own x(s=0,1); zero pads; zero its part[1]
    // so step-0's "previous update" is a no-op (keeps c=h=0).
    if (t512 < K) {
        const int t0 = diru ? (TT - 1) : 0;
        const int t1 = diru ? (TT - 2) : 1;
        xs[diru][0][t512] = xb[(size_t)t0 * K + t512];
        xs[diru][1][t512] = xb[(size_t)t1 * K + t512];
    }
    if (KP > K && t512 >= K && t512 < KP) {
        xs[diru][0][t512] = 0.f; xs[diru][1][t512] = 0.f;
        xs[diru][2][t512] = 0.f; xs[diru][3][t512] = 0.f;
    }
    (&part[diru][1][0][0])[t512] = 0.f;   // each dir zeroes its 512 floats

    float c = 0.f, hv = 0.f;
    __syncthreads();

    for (int sb = 0; sb < TT; sb += 4) {
#pragma unroll
        for (int U = 0; U < 4; ++U) {
            const int s = sb + U;   // sb%4==0 -> s&3==U, s&1==U&1 (static)

            // ---- issue prefetch of x_{s+2} (lands before the barrier) ----
            const bool pf = (s + 2 < TT) && (t512 < K);
            float xf = 0.f;
            if (pf) {
                const int tp = diru ? (TT - 3 - s) : (s + 2);
                xf = xb[(size_t)tp * K + t512];
            }

            // ---- previous step's partials -> acts for unit u=lane ----
            const float* pp0 = part[diru][(s + 1) & 1][0];
            const float* pp1 = part[diru][(s + 1) & 1][1];
            const float ai = pp0[lane]       + pp1[lane];
            const float af = pp0[64 + lane]  + pp1[64 + lane];
            const float ag = pp0[128 + lane] + pp1[128 + lane];
            const float ao = pp0[192 + lane] + pp1[192 + lane];
            const float iv = sigf(ai), fv = sigf(af);
            const float gv = tanhf_fast(ag), ov = sigf(ao);
            c = fmaf(fv, c, iv * gv);
            hv = ov * tanhf_fast(c);
            if (s && w8 == 0) {   // wave 0 of each dir-half stores its h
                const int tprev = diru ? (TT - s) : (s - 1);
                hob[(size_t)tprev * 128 + lane] = hv;   // fire-and-forget
            }

            // ---- x-part: broadcast float4 reads of this wave's K-half ----
            float ap0 = bg, ap1 = 0.f, ap2 = 0.f, ap3 = 0.f;
            const float4* xv4 = (const float4*)(xs[diru][s & 3] + halfu * KH);
#pragma unroll
            for (int q = 0; q < KH / 4; ++q) {
                const float4 xv = xv4[q];
                ap0 = fmaf(xv.x, wx[4 * q + 0], ap0);
                ap1 = fmaf(xv.y, wx[4 * q + 1], ap1);
                ap2 = fmaf(xv.z, wx[4 * q + 2], ap2);
                ap3 = fmaf(xv.w, wx[4 * q + 3], ap3);
            }

            // ---- h-part: readlane broadcast, k = halfu*32 + j (uniform) ----
#pragma unroll
            for (int j = 0; j < 32; ++j) {
                const float hk = lane_bcast(hv, halfu * 32 + j);
                if ((j & 3) == 0)      ap0 = fmaf(hk, wh[j], ap0);
                else if ((j & 3) == 1) ap1 = fmaf(hk, wh[j], ap1);
                else if ((j & 3) == 2) ap2 = fmaf(hk, wh[j], ap2);
                else                   ap3 = fmaf(hk, wh[j], ap3);
            }

            // ---- this step's partial ----
            part[diru][s & 1][halfu][G] = (ap0 + ap1) + (ap2 + ap3);

            // ---- land prefetched x in slot (s+2)&3 (static) ----
            if (pf) xs[diru][(s + 2) & 3][t512] = xf;
            __syncthreads();
        }
    }

    // epilogue: h[TT-1] from the last partials
    {
        const float* pp0 = part[diru][(TT - 1) & 1][0];
        const float* pp1 = part[diru][(TT - 1) & 1][1];
        const float ai = pp0[lane]       + pp1[lane];
        const float af = pp0[64 + lane]  + pp1[64 + lane];
        const float ag = pp0[128 + lane] + pp1[128 + lane];
        const float ao = pp0[192 + lane] + pp1[192 + lane];
        const float cf = fmaf(sigf(af), c, sigf(ai) * tanhf_fast(ag));
        const float hf = sigf(ao) * tanhf_fast(cf);
        if (w8 == 0) {
            const int tlast = diru ? 0 : (TT - 1);
            hob[(size_t)tlast * 128 + lane] = hf;
        }
    }
}

// emissions = feats @ lin_w^T + lin_b ; block tile = 64 (b,t) rows x 41 classes
__global__ __launch_bounds__(256, 2) void emis_kernel(
    const float* __restrict__ feats,  // [B*T,128]
    const float* __restrict__ lw,     // [41,128]
    const float* __restrict__ lb,     // [41]
    float* __restrict__ e)            // [B*T,41]
{
    __shared__ float sf[64 * 132];
    __shared__ float swt[41 * 132];
    const int tid = threadIdx.x;
    const size_t bt0 = (size_t)blockIdx.x * 64;

    const float4* fs = (const float4*)(feats + bt0 * 128);
#pragma unroll
    for (int q = 0; q < 8; ++q) {
        const int idx = tid + q * 256;
        const int row = idx >> 5, col = idx & 31;
        *(float4*)&sf[row * 132 + col * 4] = fs[idx];
    }
    for (int idx = tid; idx < 41 * 32; idx += 256) {
        const int row = idx >> 5, col = idx & 31;
        *(float4*)&swt[row * 132 + col * 4] = ((const float4*)lw)[idx];
    }
    __syncthreads();

    const int btg = tid >> 4;
    const int cg = tid & 15;
    const int c0 = cg * 3;
    float acc[4][3];
#pragma unroll
    for (int i = 0; i < 4; ++i)
#pragma unroll
        for (int j = 0; j < 3; ++j) acc[i][j] = 0.f;

    for (int k = 0; k < 128; k += 4) {
        float4 fv[4], wv[3];
#pragma unroll
        for (int i = 0; i < 4; ++i) fv[i] = *(const float4*)&sf[(btg * 4 + i) * 132 + k];
#pragma unroll
        for (int j = 0; j < 3; ++j) {
            const int c = (c0 + j < CC) ? (c0 + j) : (CC - 1);
            wv[j] = *(const float4*)&swt[c * 132 + k];
        }
#pragma unroll
        for (int i = 0; i < 4; ++i)
#pragma unroll
            for (int j = 0; j < 3; ++j) {
                acc[i][j] = fmaf(fv[i].x, wv[j].x, acc[i][j]);
                acc[i][j] = fmaf(fv[i].y, wv[j].y, acc[i][j]);
                acc[i][j] = fmaf(fv[i].z, wv[j].z, acc[i][j]);
                acc[i][j] = fmaf(fv[i].w, wv[j].w, acc[i][j]);
            }
    }
    __syncthreads();
    float* so = sf;
#pragma unroll
    for (int i = 0; i < 4; ++i)
#pragma unroll
        for (int j = 0; j < 3; ++j) {
            const int c = c0 + j;
            if (c < CC) so[(btg * 4 + i) * CC + c] = acc[i][j] + lb[c];
        }
    __syncthreads();
    float* eo = e + bt0 * CC;
    for (int q = tid; q < 64 * CC; q += 256) eo[q] = so[q];
}

// One wave per batch row; backpointers in LDS; in-kernel backtrace.
__global__ __launch_bounds__(64, 1) void viterbi_kernel(
    const float* __restrict__ e, const float* __restrict__ st,
    const float* __restrict__ en, const float* __restrict__ tr,
    int* __restrict__ out)
{
    const int b = blockIdx.x;
    const int lane = threadIdx.x;
    __shared__ unsigned char bp[TT][CC];
    __shared__ float sc[2][CC];
    const int c = (lane < CC) ? lane : (CC - 1);
    float trc[CC];
#pragma unroll
    for (int p = 0; p < CC; ++p) trc[p] = tr[p * CC + c];

    const float* eb = e + (size_t)b * TT * CC;
    const float NEG = -3.0e38f;
    if (lane < CC) sc[0][lane] = st[lane] + eb[lane];
    __syncthreads();

    for (int t = 1; t < TT; ++t) {
        const float* scp = sc[(t - 1) & 1];
        float best = NEG;
        int bi = 0;
#pragma unroll
        for (int p = 0; p < CC; ++p) {
            const float v = scp[p] + trc[p];
            if (v > best) { best = v; bi = p; }   // strict > : first-index ties
        }
        if (lane < CC) {
            sc[t & 1][lane] = best + eb[(size_t)t * CC + lane];
            bp[t][lane] = (unsigned char)bi;
        }
        __syncthreads();
    }

    float fin = (lane < CC) ? sc[(TT - 1) & 1][lane] + en[lane] : NEG;
    int idx = lane;
#pragma unroll
    for (int off = 32; off; off >>= 1) {
        const float v2 = __shfl_down(fin, off, 64);
        const int i2 = __shfl_down(idx, off, 64);
        if (v2 > fin || (v2 == fin && i2 < idx)) { fin = v2; idx = i2; }
    }
    int tag = __shfl(idx, 0, 64);
    if (lane == 0) {
        int* ob = out + (size_t)b * TT;
        ob[TT - 1] = tag;
        for (int t = TT - 1; t >= 1; --t) {
            tag = bp[t][tag];
            ob[t - 1] = tag;
        }
    }
}

extern "C" void kernel_launch(void* const* d_in, const int* in_sizes, int n_in,
                              void* d_out, int out_size, void* d_ws, size_t ws_size,
                              hipStream_t stream) {
    const float* x       = (const float*)d_in[0];   // [B,T,39]
    const float* w_ih_l0 = (const float*)d_in[1];   // [2,256,39]
    const float* w_hh_l0 = (const float*)d_in[2];   // [2,256,64]
    const float* b_l0    = (const float*)d_in[3];   // [2,256]
    const float* w_ih_r  = (const float*)d_in[4];   // [2,2,256,128]
    const float* w_hh_r  = (const float*)d_in[5];   // [2,2,256,64]
    const float* b_r     = (const float*)d_in[6];   // [2,2,256]
    const float* lin_w   = (const float*)d_in[7];   // [41,128]
    const float* lin_b   = (const float*)d_in[8];   // [41]
    const float* crf_s   = (const float*)d_in[9];   // [41]
    const float* crf_e   = (const float*)d_in[10];  // [41]
    const float* crf_t   = (const float*)d_in[11];  // [41,41]
    int* out = (int*)d_out;

    float* buf0 = (float*)d_ws;                         // [B,T,128] = 128 MiB
    float* buf1 = buf0 + (size_t)BB * TT * 128;         // [B,T,128] = 128 MiB

    // 256 blocks (one per batch row, both dirs inside) = exactly 1 block/CU
    // layer 0 (input dim 39): buf0 <- x
    lstm_dual<39><<<BB, 1024, 0, stream>>>(x, w_ih_l0, w_hh_l0, b_l0, buf0);
    // layer 1: buf1 <- buf0
    lstm_dual<128><<<BB, 1024, 0, stream>>>(buf0, w_ih_r, w_hh_r, b_r, buf1);
    // layer 2: buf0 <- buf1
    lstm_dual<128><<<BB, 1024, 0, stream>>>(
        buf1, w_ih_r + 2 * 256 * 128, w_hh_r + 2 * 256 * 64, b_r + 2 * 256, buf0);
    // emissions: buf1 <- buf0, [B*T,41]
    emis_kernel<<<BB * TT / 64, 256, 0, stream>>>(buf0, lin_w, lin_b, buf1);
    // viterbi + backtrace
    viterbi_kernel<<<BB, 64, 0, stream>>>(buf1, crf_s, crf_e, crf_t, out);
}